// Round 1
// baseline (15.897 us; speedup 1.0000x reference)
//
#include <hip/hip_runtime.h>

// Gather: out[b, j, :] = x[b, idx[b, j], :]
// x:   [B=16, S=8192, D=256] float32
// idx: [B=16, REF_LEN=2048] int (sorted per batch)
// out: [B=16, REF_LEN=2048, D=256] float32
//
// One 64-lane wave copies one row: 64 lanes x float4 (16B) = 1024B = D*4B.

constexpr int B = 16;
constexpr int S = 8192;
constexpr int D = 256;
constexpr int REF_LEN = 2048;
constexpr int ROWS = B * REF_LEN;          // 32768 rows
constexpr int F4_PER_ROW = D / 4;          // 64 float4 per row

__global__ __launch_bounds__(256) void gather_rows_kernel(
    const float4* __restrict__ x,
    const int* __restrict__ idx,
    float4* __restrict__ out) {
    // 4 waves per block, one row per wave
    const int wave = blockIdx.x * 4 + (threadIdx.x >> 6);
    const int lane = threadIdx.x & 63;
    if (wave >= ROWS) return;

    const int b = wave >> 11;        // / REF_LEN
    const int src_row = idx[wave];   // idx[b][j]

    const size_t src_off = ((size_t)b * S + (size_t)src_row) * F4_PER_ROW + lane;
    const size_t dst_off = (size_t)wave * F4_PER_ROW + lane;
    out[dst_off] = x[src_off];
}

extern "C" void kernel_launch(void* const* d_in, const int* in_sizes, int n_in,
                              void* d_out, int out_size, void* d_ws, size_t ws_size,
                              hipStream_t stream) {
    const float4* x = (const float4*)d_in[0];
    const int* idx = (const int*)d_in[1];
    float4* out = (float4*)d_out;

    const int blocks = ROWS / 4;  // 8192
    gather_rows_kernel<<<blocks, 256, 0, stream>>>(x, idx, out);
}

// Round 3
// 14.643 us; speedup vs baseline: 1.0856x; 1.0856x over previous
//
#include <hip/hip_runtime.h>

// Gather: out[b, j, :] = x[b, idx[b, j], :]
// x:   [B=16, S=8192, D=256] float32
// idx: [B=16, REF_LEN=2048] int32 (sorted per batch)
// out: [B=16, REF_LEN=2048, D=256] float32
//
// 2048 blocks x 256 threads, 4 float4 per thread with phase-split
// load/store for memory-level parallelism. Native vector type so
// __builtin_nontemporal_store/load accept it.

typedef float vfloat4 __attribute__((ext_vector_type(4)));

constexpr int B = 16;
constexpr int S = 8192;
constexpr int D = 256;
constexpr int REF_LEN = 2048;
constexpr int ROWS = B * REF_LEN;              // 32768 rows
constexpr int F4_PER_ROW = D / 4;              // 64 float4 per row
constexpr int TOTAL_F4 = ROWS * F4_PER_ROW;    // 2,097,152
constexpr int THREADS = 256;
constexpr int BLOCKS = 2048;
constexpr int PER_THREAD = TOTAL_F4 / (THREADS * BLOCKS);  // 4
constexpr int STRIDE = THREADS * BLOCKS;       // 524288

__global__ __launch_bounds__(THREADS) void gather_rows_kernel(
    const vfloat4* __restrict__ x,
    const int* __restrict__ idx,
    vfloat4* __restrict__ out) {
    const int tid = blockIdx.x * THREADS + threadIdx.x;

    int e[PER_THREAD];
    int src[PER_THREAD];
    vfloat4 v[PER_THREAD];

    // Phase 1: idx loads (wave-uniform per k: e>>6 constant across the wave)
    #pragma unroll
    for (int k = 0; k < PER_THREAD; ++k) {
        e[k] = tid + k * STRIDE;
        src[k] = idx[e[k] >> 6];           // row index within batch
    }

    // Phase 2: gather loads — 4 independent chains in flight
    #pragma unroll
    for (int k = 0; k < PER_THREAD; ++k) {
        const int row = e[k] >> 6;         // global output row
        const int b = row >> 11;           // / REF_LEN
        const int lane_in_row = e[k] & (F4_PER_ROW - 1);
        const size_t src_off = (((size_t)b * S + (size_t)src[k]) << 6) + lane_in_row;
        v[k] = x[src_off];
    }

    // Phase 3: nontemporal stores (write-once output)
    #pragma unroll
    for (int k = 0; k < PER_THREAD; ++k) {
        __builtin_nontemporal_store(v[k], &out[e[k]]);
    }
}

extern "C" void kernel_launch(void* const* d_in, const int* in_sizes, int n_in,
                              void* d_out, int out_size, void* d_ws, size_t ws_size,
                              hipStream_t stream) {
    const vfloat4* x = (const vfloat4*)d_in[0];
    const int* idx = (const int*)d_in[1];
    vfloat4* out = (vfloat4*)d_out;

    gather_rows_kernel<<<BLOCKS, THREADS, 0, stream>>>(x, idx, out);
}